// Round 9
// baseline (417.993 us; speedup 1.0000x reference)
//
#include <hip/hip_runtime.h>
#include <math.h>

#ifndef M_PI
#define M_PI 3.14159265358979323846
#endif

constexpr int S_LEN    = 176400;
constexpr int NFFT     = 2048;
constexpr int NC       = 1024;
constexpr int HOP_     = 441;
constexpr int T_FRAMES = 401;
constexpr int F_BINS   = 1025;
constexpr int F_STRIDE = 1028;     // fp32 spec row stride (16B aligned)
constexpr int N_CH     = 64;
constexpr float EPS_   = 1e-8f;
constexpr float C1_    = 0.0004f;
constexpr float C2_    = 0.0036f;
constexpr float COV_NORM_ = 49.0f / 48.0f;

// workspace float offsets
constexpr int WIN_OFF  = 0;        // float[2048] hann window
constexpr int TWG_OFF  = 2048;     // float2[768]  tw[e] = exp(-2pi i e/1024)
constexpr int UTW_OFF  = 3584;     // float2[1025] exp(-i pi r/1024)
constexpr int SPEC_OFF = 5696;
constexpr int RPB_     = 10;
constexpr int N_CHUNKS = 40;

#define WAVE_SYNC() asm volatile("s_waitcnt lgkmcnt(0)" ::: "memory")

// LDS bank swizzle (R8-proven): phys(a) = a ^ ((a>>2)&15).
__device__ __forceinline__ int phys(int i) { return i ^ ((i >> 2) & 15); }

__device__ __forceinline__ float2 cadd(float2 a, float2 b){ return make_float2(a.x+b.x, a.y+b.y); }
__device__ __forceinline__ float2 csub(float2 a, float2 b){ return make_float2(a.x-b.x, a.y-b.y); }
__device__ __forceinline__ float2 cmul(float2 a, float2 b){ return make_float2(a.x*b.x-a.y*b.y, a.x*b.y+a.y*b.x); }

__global__ __launch_bounds__(256) void init_tables_kernel(float* __restrict__ ws, float* __restrict__ out) {
    const int idx = blockIdx.x * 256 + threadIdx.x;
    if (idx < 64) out[idx] = 0.0f;
    if (idx < NFFT) {
        ws[WIN_OFF + idx] = 0.5f - 0.5f * cosf((float)(2.0 * M_PI / NFFT) * (float)idx);
    }
    if (idx < 768) {
        float ang = -2.0f * (float)M_PI * (float)idx / (float)NC;
        float s, c; sincosf(ang, &s, &c);
        ws[TWG_OFF + 2*idx] = c; ws[TWG_OFF + 2*idx+1] = s;
    }
    if (idx < F_BINS) {
        float ang = -(float)M_PI * (float)idx / (float)NC;
        float s, c; sincosf(ang, &s, &c);
        ws[UTW_OFF + 2*idx] = c; ws[UTW_OFF + 2*idx+1] = s;
    }
}

// Block-wide 1024-pt complex radix-4 Stockham (R8: 216us, VALU 82%, conflicts ~0),
// + block-uniform in-range fast path for the pack (reflect math on edge spans only).
__global__ __launch_bounds__(256, 8) void stft_mag_kernel(
    const float* __restrict__ x0, const float* __restrict__ x1,
    float* __restrict__ ws, int ch0, int nch, int swizzle)
{
    __shared__ float2 bufA[NC];
    __shared__ float2 bufB[NC];

    const int tid = threadIdx.x;

    int ch, which, t;
    if (swizzle) {
        int g = blockIdx.x;
        ch    = ch0 + (g & 7) * 8 + ((g >> 3) & 7);
        which = (g >> 6) & 1;
        t     = g >> 7;
    } else {
        int bx = blockIdx.x;
        which = bx / T_FRAMES;
        t     = bx - which * T_FRAMES;
        ch    = ch0 + blockIdx.y;
    }

    const float* __restrict__ xin = (which ? x1 : x0) + (size_t)ch * S_LEN;
    const float*  __restrict__ win = ws + WIN_OFF;
    const float2* __restrict__ twg = (const float2*)(ws + TWG_OFF);
    const float2* __restrict__ utw = (const float2*)(ws + UTW_OFF);

    // ---- pack: flat float index n over [0,2048); complex ci = n>>1 (swizzled)
    const int base = t * HOP_ - NFFT / 2;
    float* bufAf = (float*)bufA;
    #pragma unroll
    for (int k = 0; k < NFFT / 256; ++k) {
        int n = k * 256 + tid;
        int s0 = base + k * 256;              // block-uniform span start
        float v;
        if (s0 >= 0 && s0 + 256 <= S_LEN) {   // uniform fast path
            v = xin[s0 + tid] * win[n];
        } else {
            int j = s0 + tid;
            j = (j < 0) ? -j : j;
            j = (j >= S_LEN) ? (2 * S_LEN - 2 - j) : j;
            v = xin[j] * win[n];
        }
        int ci = n >> 1;
        bufAf[2 * phys(ci) + (n & 1)] = v;
    }
    __syncthreads();

    // ---- 5-stage radix-4 Stockham DIF
    float2* A = bufA;
    float2* B = bufB;
    #pragma unroll
    for (int i = 0; i < 5; ++i) {
        const int s_ = 1 << (2 * i);
        const int q  = tid & (s_ - 1);
        const int ps = tid - q;            // p * s

        float2 x0c = A[phys(tid)];
        float2 x1c = A[phys(tid + 256)];
        float2 x2c = A[phys(tid + 512)];
        float2 x3c = A[phys(tid + 768)];

        float2 t0 = cadd(x0c, x2c);
        float2 t1 = csub(x0c, x2c);
        float2 t2 = cadd(x1c, x3c);
        float2 t3 = csub(x1c, x3c);

        float2 y0 = cadd(t0, t2);
        float2 y2 = csub(t0, t2);
        float2 y1 = make_float2(t1.x + t3.y, t1.y - t3.x);   // t1 - i*t3
        float2 y3 = make_float2(t1.x - t3.y, t1.y + t3.x);   // t1 + i*t3

        float2 w1 = twg[ps];
        float2 w2 = twg[2 * ps];
        float2 w3 = twg[3 * ps];

        float2 z1 = cmul(y1, w1);
        float2 z2 = cmul(y2, w2);
        float2 z3 = cmul(y3, w3);

        const int o = q + 4 * ps;
        B[phys(o)]          = y0;
        B[phys(o + s_)]     = z1;
        B[phys(o + 2 * s_)] = z2;
        B[phys(o + 3 * s_)] = z3;
        __syncthreads();
        float2* tmp = A; A = B; B = tmp;
    }

    // ---- real-FFT unpack + magnitude + fp32 coalesced stores
    float* __restrict__ sout =
        ws + SPEC_OFF + ((size_t)which * nch + (size_t)(ch - ch0)) * (size_t)T_FRAMES * F_STRIDE
                      + (size_t)t * F_STRIDE;
    #pragma unroll
    for (int k = 0; k < 5; ++k) {
        int r = k * 256 + tid;
        if (k < 4 || tid == 0) {
            float2 Zr = A[phys(r & (NC - 1))];
            float2 Zn = A[phys((NC - r) & (NC - 1))];
            float Ex = 0.5f * (Zr.x + Zn.x);
            float Ey = 0.5f * (Zr.y - Zn.y);
            float Ox = 0.5f * (Zr.y + Zn.y);
            float Oy = 0.5f * (Zn.x - Zr.x);
            float2 wu = utw[r];
            float Xx = Ex + wu.x * Ox - wu.y * Oy;
            float Xy = Ey + wu.x * Oy + wu.y * Ox;
            sout[r] = sqrtf(fmaxf(Xx * Xx + Xy * Xy, EPS_));
        }
    }
}

// SSIM, barrier-free: each wave owns a 256-col output slice and computes all
// vertical sums it reads (cols [256w, 256w+262); lanes 58..63 carry one extra
// boundary column each). All LDS traffic is intra-wave -> per-row syncs are
// wave-local lgkmcnt fences, no s_barrier in the row loop.
__global__ __launch_bounds__(256) void ssim_kernel(
    const float* __restrict__ ws, float* __restrict__ out,
    int ch0, int nch)
{
    __shared__ float S[5][4][328];
    __shared__ double red[256];

    const int tid = threadIdx.x;
    const int wv  = tid >> 6;
    const int l   = tid & 63;
    const int cg  = blockIdx.y;
    const int ch  = ch0 + cg;
    const float* __restrict__ spec = ws + SPEC_OFF;
    const size_t per_ch = (size_t)T_FRAMES * F_STRIDE;
    const float* __restrict__ X = spec + (size_t)cg * per_ch;
    const float* __restrict__ Y = spec + ((size_t)nch + cg) * per_ch;

    const int t_begin = 3 + blockIdx.x * RPB_;
    const int t_end_  = min(t_begin + RPB_, T_FRAMES - 3);

    const int colb = (wv << 8) + (l << 2);      // own float4 base col (abs)
    const int eI   = l - 58;                    // 0..5 for lanes 58..63
    const int ecol = (wv << 8) + 256 + eI;      // extra boundary col (abs)
    const bool has_e = (eI >= 0) && (ecol <= 1024);
    const int ea = 320 + eI + (eI >> 2);        // LDS addr of extra col

    const float inv49 = 1.0f / 49.0f;
    double acc = 0.0;

    float sx[4]={0,0,0,0}, sy[4]={0,0,0,0}, sxx[4]={0,0,0,0},
          syy[4]={0,0,0,0}, sxy[4]={0,0,0,0};
    float es[5]={0,0,0,0,0};                    // extra col rolling sums

    // ramp rows [t_begin-3, t_begin+2]
    for (int rr = t_begin - 3; rr < t_begin + 3; ++rr) {
        float4 xv = *(const float4*)(X + (size_t)rr * F_STRIDE + colb);
        float4 yv = *(const float4*)(Y + (size_t)rr * F_STRIDE + colb);
        float xa[4] = {xv.x, xv.y, xv.z, xv.w}, ya[4] = {yv.x, yv.y, yv.z, yv.w};
        #pragma unroll
        for (int c = 0; c < 4; ++c) {
            sx[c] += xa[c]; sy[c] += ya[c];
            sxx[c] += xa[c]*xa[c]; syy[c] += ya[c]*ya[c]; sxy[c] += xa[c]*ya[c];
        }
        if (has_e) {
            float xe = X[(size_t)rr * F_STRIDE + ecol];
            float ye = Y[(size_t)rr * F_STRIDE + ecol];
            es[0] += xe; es[1] += ye; es[2] += xe*xe; es[3] += ye*ye; es[4] += xe*ye;
        }
    }

    // prefetch add-row (t_begin+3) and sub-row (t_begin-3)
    float4 ax, ay, bx, by; float eax=0, eay=0, ebx=0, eby=0;
    ax = *(const float4*)(X + (size_t)(t_begin + 3) * F_STRIDE + colb);
    ay = *(const float4*)(Y + (size_t)(t_begin + 3) * F_STRIDE + colb);
    bx = *(const float4*)(X + (size_t)(t_begin - 3) * F_STRIDE + colb);
    by = *(const float4*)(Y + (size_t)(t_begin - 3) * F_STRIDE + colb);
    if (has_e) {
        eax = X[(size_t)(t_begin + 3) * F_STRIDE + ecol];
        eay = Y[(size_t)(t_begin + 3) * F_STRIDE + ecol];
        ebx = X[(size_t)(t_begin - 3) * F_STRIDE + ecol];
        eby = Y[(size_t)(t_begin - 3) * F_STRIDE + ecol];
    }

    const int p5 = 5 * l;

    for (int t = t_begin; t < t_end_; ++t) {
        // add row t+3, publish to own wave's slice
        {
            float xa[4] = {ax.x, ax.y, ax.z, ax.w}, ya[4] = {ay.x, ay.y, ay.z, ay.w};
            #pragma unroll
            for (int c = 0; c < 4; ++c) {
                sx[c] += xa[c]; sy[c] += ya[c];
                sxx[c] += xa[c]*xa[c]; syy[c] += ya[c]*ya[c]; sxy[c] += xa[c]*ya[c];
                S[0][wv][p5+c] = sx[c];  S[1][wv][p5+c] = sy[c];
                S[2][wv][p5+c] = sxx[c]; S[3][wv][p5+c] = syy[c]; S[4][wv][p5+c] = sxy[c];
            }
            if (has_e) {
                es[0] += eax; es[1] += eay; es[2] += eax*eax; es[3] += eay*eay; es[4] += eax*eay;
                S[0][wv][ea] = es[0]; S[1][wv][ea] = es[1];
                S[2][wv][ea] = es[2]; S[3][wv][ea] = es[3]; S[4][wv][ea] = es[4];
            }
        }
        WAVE_SYNC();

        // subtract row t-3 (registers) + prefetch next rows (overlaps taps below)
        {
            float xa[4] = {bx.x, bx.y, bx.z, bx.w}, ya[4] = {by.x, by.y, by.z, by.w};
            #pragma unroll
            for (int c = 0; c < 4; ++c) {
                sx[c] -= xa[c]; sy[c] -= ya[c];
                sxx[c] -= xa[c]*xa[c]; syy[c] -= ya[c]*ya[c]; sxy[c] -= xa[c]*ya[c];
            }
            if (has_e) {
                es[0] -= ebx; es[1] -= eby; es[2] -= ebx*ebx; es[3] -= eby*eby; es[4] -= ebx*eby;
            }
        }
        if (t + 1 < t_end_) {
            ax = *(const float4*)(X + (size_t)(t + 4) * F_STRIDE + colb);
            ay = *(const float4*)(Y + (size_t)(t + 4) * F_STRIDE + colb);
            bx = *(const float4*)(X + (size_t)(t - 2) * F_STRIDE + colb);
            by = *(const float4*)(Y + (size_t)(t - 2) * F_STRIDE + colb);
            if (has_e) {
                eax = X[(size_t)(t + 4) * F_STRIDE + ecol];
                eay = Y[(size_t)(t + 4) * F_STRIDE + ecol];
                ebx = X[(size_t)(t - 2) * F_STRIDE + ecol];
                eby = Y[(size_t)(t - 2) * F_STRIDE + ecol];
            }
        }

        // taps (own slice only) + rolling 7-window + SSIM formula
        {
            float tx[10], ty[10], txx[10], tyy[10], txy[10];
            #pragma unroll
            for (int d = 0; d < 10; ++d) {
                int q = p5 + d + (d >> 2);     // a(4l+d) within own slice
                tx[d] = S[0][wv][q]; ty[d] = S[1][wv][q];
                txx[d] = S[2][wv][q]; tyy[d] = S[3][wv][q]; txy[d] = S[4][wv][q];
            }
            float wx  = tx[0]+tx[1]+tx[2]+tx[3]+tx[4]+tx[5]+tx[6];
            float wy  = ty[0]+ty[1]+ty[2]+ty[3]+ty[4]+ty[5]+ty[6];
            float wxx = txx[0]+txx[1]+txx[2]+txx[3]+txx[4]+txx[5]+txx[6];
            float wyy = tyy[0]+tyy[1]+tyy[2]+tyy[3]+tyy[4]+tyy[5]+tyy[6];
            float wxy = txy[0]+txy[1]+txy[2]+txy[3]+txy[4]+txy[5]+txy[6];
            #pragma unroll
            for (int c = 0; c < 4; ++c) {
                if (colb + 3 + c <= 1021) {
                    float ux  = wx * inv49, uy  = wy * inv49;
                    float uxx = wxx * inv49, uyy = wyy * inv49, uxy = wxy * inv49;
                    float vx  = COV_NORM_ * (uxx - ux * ux);
                    float vy  = COV_NORM_ * (uyy - uy * uy);
                    float vxy = COV_NORM_ * (uxy - ux * uy);
                    float Sv = ((2.f * ux * uy + C1_) * (2.f * vxy + C2_)) /
                               ((ux * ux + uy * uy + C1_) * (vx + vy + C2_));
                    acc += (double)Sv;
                }
                if (c < 3) {
                    wx  += tx[c+7]  - tx[c];
                    wy  += ty[c+7]  - ty[c];
                    wxx += txx[c+7] - txx[c];
                    wyy += tyy[c+7] - tyy[c];
                    wxy += txy[c+7] - txy[c];
                }
            }
        }
        WAVE_SYNC();
    }

    red[tid] = acc;
    __syncthreads();
    for (int off = 128; off > 0; off >>= 1) {
        if (tid < off) red[tid] += red[tid + off];
        __syncthreads();
    }
    if (tid == 0) {
        atomicAdd(&out[ch], (float)(red[0] / (395.0 * 1019.0)));
    }
}

extern "C" void kernel_launch(void* const* d_in, const int* in_sizes, int n_in,
                              void* d_out, int out_size, void* d_ws, size_t ws_size,
                              hipStream_t stream) {
    const float* x0 = (const float*)d_in[0];   // output
    const float* x1 = (const float*)d_in[1];   // target
    float* out = (float*)d_out;
    float* ws  = (float*)d_ws;

    const size_t table_bytes  = (size_t)SPEC_OFF * sizeof(float);
    const size_t per_ch_bytes = (size_t)2 * T_FRAMES * F_STRIDE * sizeof(float);
    int G = (int)((ws_size - table_bytes) / per_ch_bytes);
    if (G > N_CH) G = N_CH;
    if (G < 1)    G = 1;

    init_tables_kernel<<<dim3(16), dim3(256), 0, stream>>>(ws, out);

    for (int ch0 = 0; ch0 < N_CH; ch0 += G) {
        const int nch = (N_CH - ch0 < G) ? (N_CH - ch0) : G;

        if (nch == 64) {
            stft_mag_kernel<<<dim3(T_FRAMES * 128), dim3(256), 0, stream>>>(x0, x1, ws, ch0, nch, 1);
        } else {
            stft_mag_kernel<<<dim3(2 * T_FRAMES, nch), dim3(256), 0, stream>>>(x0, x1, ws, ch0, nch, 0);
        }

        dim3 g2(N_CHUNKS, nch);
        ssim_kernel<<<g2, 256, 0, stream>>>(ws, out, ch0, nch);
    }
}